// Round 13
// baseline (1561.525 us; speedup 1.0000x reference)
//
#include <hip/hip_runtime.h>
#include <stdint.h>
#include <stddef.h>

typedef unsigned short u16;
typedef __attribute__((ext_vector_type(8))) short short8;
typedef __attribute__((ext_vector_type(4))) float f32x4;

#define N_NODES 50000
#define N_EDGES 800000
#define N_GRAPHS 2000
#define EMB 300
#define EMB_P 320
#define HID 600
#define HID_P 640
#define NP2 384
#define M_P 50176
#define G_P 2048
#define FEAT 512
#define OUTD 256
#define NLAYER 5

// ---- bf16 cvt arena offsets ----
#define OFF_EMB1 0
#define N_EMB1   (119 * EMB)
#define OFF_EMB2 (OFF_EMB1 + N_EMB1)
#define N_EMB2   (3 * EMB)
#define OFF_E1   (OFF_EMB2 + N_EMB2)
#define N_E1     (NLAYER * 5 * EMB)
#define OFF_E2   (OFF_E1 + N_E1)
#define N_E2     (NLAYER * 3 * EMB)
#define OFF_W1   (OFF_E2 + N_E2)
#define N_W1     (NLAYER * EMB * HID)
#define OFF_B1   (OFF_W1 + N_W1)
#define N_B1     (NLAYER * HID)
#define OFF_W2   (OFF_B1 + N_B1)
#define N_W2     (NLAYER * HID * EMB)
#define OFF_B2   (OFF_W2 + N_W2)
#define N_B2     (NLAYER * EMB)
#define OFF_FW   (OFF_B2 + N_B2)
#define N_FW     (EMB * FEAT)
#define OFF_FB   (OFF_FW + N_FW)
#define N_FB     (FEAT)
#define OFF_P0W  (OFF_FB + N_FB)
#define N_P0W    (FEAT * (FEAT / 2))
#define OFF_P0B  (OFF_P0W + N_P0W)
#define N_P0B    (FEAT / 2)
#define OFF_P1W  (OFF_P0B + N_P0B)
#define N_P1W    ((FEAT / 2) * (FEAT / 2))
#define OFF_P1B  (OFF_P1W + N_P1W)
#define N_P1B    (FEAT / 2)
#define OFF_P2W  (OFF_P1B + N_P1B)
#define N_P2W    ((FEAT / 2) * OUTD)
#define OFF_P2B  (OFF_P2W + N_P2W)
#define N_P2B    (OUTD)
#define CVT_TOTAL (OFF_P2B + N_P2B)

// ---- transposed-weight arena offsets ----
#define WOFF_W1T 0
#define WN_W1T   (NLAYER * HID_P * EMB_P)
#define WOFF_W2T (WOFF_W1T + WN_W1T)
#define WN_W2T   (NLAYER * NP2 * HID_P)
#define WOFF_FWT (WOFF_W2T + WN_W2T)
#define WN_FWT   (FEAT * EMB_P)
#define WOFF_P0T (WOFF_FWT + WN_FWT)
#define WN_P0T   (OUTD * FEAT)
#define WOFF_P1T (WOFF_P0T + WN_P0T)
#define WN_P1T   (OUTD * OUTD)
#define WOFF_P2T (WOFF_P1T + WN_P1T)
#define WN_P2T   (OUTD * OUTD)
#define WOFF_B1P (WOFF_P2T + WN_P2T)
#define WN_B1P   (NLAYER * HID_P)
#define WOFF_B2P (WOFF_B1P + WN_B1P)
#define WN_B2P   (NLAYER * NP2)
#define W_TOTAL  (WOFF_B2P + WN_B2P)

__device__ __forceinline__ float b2f(u16 u) {
    union { unsigned int i; float f; } c; c.i = ((unsigned int)u) << 16; return c.f;
}
__device__ __forceinline__ u16 f2b(float f) {
    union { float f; unsigned int i; } c; c.f = f;
    unsigned int x = c.i;
    unsigned int lsb = (x >> 16) & 1u;
    x += 0x7fffu + lsb;
    return (u16)(x >> 16);
}
__device__ __forceinline__ int geti(const int* __restrict__ p, long k, int iw) {
    return p[k << iw];
}
// async global->LDS, 16B per lane; lds dest wave-uniform base (HW adds lane*16B)
__device__ __forceinline__ void gll16(const u16* g, u16* l) {
    __builtin_amdgcn_global_load_lds((const __attribute__((address_space(1))) void*)g,
                                     (__attribute__((address_space(3))) void*)l, 16, 0, 0);
}

// ---------------- dtype detection ----------------
__global__ __launch_bounds__(256) void detect_kernel(const void* __restrict__ emb1_raw,
                                                     const int* __restrict__ ei_raw,
                                                     int* __restrict__ flags) {
    __shared__ int cnt_s;
    __shared__ int nz_s;
    int tid = threadIdx.x;
    if (tid == 0) { cnt_s = 0; nz_s = 0; }
    __syncthreads();
    const u16* u = (const u16*)emb1_raw;
    int local = 0;
#pragma unroll
    for (int j = 0; j < 8; j++) {
        u16 w = u[2 * (tid * 8 + j)];
        int e = (w >> 7) & 0xFF;
        if (w == 0 || (e >= 90 && e <= 130)) local++;
    }
    atomicAdd(&cnt_s, local);
    int v = ei_raw[2 * tid + 1];
    if (v != 0) atomicOr(&nz_s, 1);
    __syncthreads();
    if (tid == 0) {
        flags[0] = (cnt_s < 1600) ? 1 : 0;
        flags[1] = nz_s ? 0 : 1;
    }
}

// ---------------- convert float params to bf16 arena ----------------
struct CvtArgs { const void* src[16]; };
__constant__ int cvt_off[17] = {OFF_EMB1, OFF_EMB2, OFF_E1, OFF_E2, OFF_W1, OFF_B1,
                                OFF_W2, OFF_B2, OFF_FW, OFF_FB, OFF_P0W, OFF_P0B,
                                OFF_P1W, OFF_P1B, OFF_P2W, OFF_P2B, CVT_TOTAL};

__global__ __launch_bounds__(256) void cvt_all(CvtArgs args, u16* __restrict__ dst,
                                               const int* __restrict__ flags) {
    int idx = blockIdx.x * 256 + threadIdx.x;
    if (idx >= CVT_TOTAL) return;
    int fp32 = flags[0];
    int t = 0;
#pragma unroll
    for (int i = 0; i < 16; i++) {
        if (idx >= cvt_off[i + 1]) t = i + 1;
    }
    int off = idx - cvt_off[t];
    u16 v;
    if (fp32) v = f2b(((const float*)args.src[t])[off]);
    else      v = ((const u16*)args.src[t])[off];
    dst[idx] = v;
}

// ---------------- combined weight transpose+pad ----------------
struct WSeg { int srcOff, Kin, Nin, Kd, Nd, bias; };
__constant__ int wseg_cum[9] = {WOFF_W1T, WOFF_W2T, WOFF_FWT, WOFF_P0T, WOFF_P1T,
                                WOFF_P2T, WOFF_B1P, WOFF_B2P, W_TOTAL};
__constant__ WSeg wsegs[8] = {
    {OFF_W1,  EMB, HID,  EMB_P, HID_P, 0},
    {OFF_W2,  HID, EMB,  HID_P, NP2,   0},
    {OFF_FW,  EMB, FEAT, EMB_P, FEAT,  0},
    {OFF_P0W, FEAT, OUTD, FEAT, OUTD,  0},
    {OFF_P1W, OUTD, OUTD, OUTD, OUTD,  0},
    {OFF_P2W, OUTD, OUTD, OUTD, OUTD,  0},
    {OFF_B1,  HID, 0, 0, HID_P, 1},
    {OFF_B2,  EMB, 0, 0, NP2,   1},
};

__global__ __launch_bounds__(256) void tpad_all(const u16* __restrict__ cbuf,
                                                u16* __restrict__ wbuf) {
    int idx = blockIdx.x * 256 + threadIdx.x;
    if (idx >= W_TOTAL) return;
    int t = 0;
#pragma unroll
    for (int i = 0; i < 8; i++) {
        if (idx >= wseg_cum[i + 1]) t = i + 1;
    }
    WSeg sg = wsegs[t];
    int i = idx - wseg_cum[t];
    u16 v = 0;
    if (sg.bias) {
        int n = i % sg.Nd, l = i / sg.Nd;
        if (n < sg.Kin) v = cbuf[sg.srcOff + l * sg.Kin + n];
    } else {
        int k = i % sg.Kd;
        int r = i / sg.Kd;
        int n = r % sg.Nd, l = r / sg.Nd;
        if (k < sg.Kin && n < sg.Nin) v = cbuf[sg.srcOff + ((long)l * sg.Kin + k) * sg.Nin + n];
    }
    wbuf[idx] = v;
}

// ---------------- CSR build ----------------
__global__ void count_edges(const int* __restrict__ ei, const int* __restrict__ ea,
                            int* __restrict__ deg, int* __restrict__ Ccnt,
                            const int* __restrict__ flags) {
    int e = blockIdx.x * 256 + threadIdx.x;
    if (e >= N_EDGES) return;
    int iw = flags[1];
    int dst = geti(ei, (long)N_EDGES + e, iw);
    if (dst >= 0 && dst < N_NODES) atomicAdd(&deg[dst], 1);
    int a = geti(ea, 2L * e, iw), b = geti(ea, 2L * e + 1, iw);
    if (dst >= 0 && dst < N_NODES && a >= 0 && a < 3 && b >= 0 && b < 3)
        atomicAdd(&Ccnt[dst * 16 + a * 3 + b], 1);
}

__global__ __launch_bounds__(1024) void scan50k(const int* __restrict__ deg,
                                                int* __restrict__ offsets,
                                                int* __restrict__ cursor) {
    __shared__ int buf[1024];
    __shared__ int carry_s;
    int tid = threadIdx.x;
    if (tid == 0) { carry_s = 0; offsets[0] = 0; }
    __syncthreads();
    for (int base = 0; base < N_NODES; base += 1024) {
        int v = (base + tid < N_NODES) ? deg[base + tid] : 0;
        buf[tid] = v;
        __syncthreads();
        for (int off = 1; off < 1024; off <<= 1) {
            int t = (tid >= off) ? buf[tid - off] : 0;
            __syncthreads();
            buf[tid] += t;
            __syncthreads();
        }
        int incl = carry_s + buf[tid];
        if (base + tid < N_NODES) {
            offsets[base + tid + 1] = incl;
            cursor[base + tid] = incl - v;
        }
        __syncthreads();
        if (tid == 0) carry_s += buf[1023];
        __syncthreads();
    }
}

__global__ void fill_csr(const int* __restrict__ ei, int* __restrict__ cursor,
                         int* __restrict__ csr_src, const int* __restrict__ flags) {
    int e = blockIdx.x * 256 + threadIdx.x;
    if (e >= N_EDGES) return;
    int iw = flags[1];
    int src = geti(ei, (long)e, iw);
    int dst = geti(ei, (long)N_EDGES + e, iw);
    if (dst < 0 || dst >= N_NODES) return;
    int pos = atomicAdd(&cursor[dst], 1);
    if (pos >= 0 && pos < N_EDGES) csr_src[pos] = src;
}

// sort each node's src list ascending -> concurrent blocks sweep correlated
// src windows -> L2/L3 temporal locality for the gather
__global__ void sort_csr(const int* __restrict__ offsets, int* __restrict__ csr_src) {
    int n = blockIdx.x * 256 + threadIdx.x;
    if (n >= N_NODES) return;
    int b = offsets[n], e = offsets[n + 1];
    for (int i = b + 1; i < e; i++) {
        int v = csr_src[i];
        int j = i - 1;
        while (j >= b && csr_src[j] > v) { csr_src[j + 1] = csr_src[j]; j--; }
        csr_src[j + 1] = v;
    }
}

// ---------------- initial embedding ----------------
__global__ __launch_bounds__(256) void embed_kernel(const int* __restrict__ x,
                                                    const u16* __restrict__ emb1,
                                                    const u16* __restrict__ emb2,
                                                    u16* __restrict__ h,
                                                    const int* __restrict__ flags) {
    int wave = threadIdx.x >> 6, lane = threadIdx.x & 63;
    int n = blockIdx.x * 4 + wave;
    int iw = flags[1];
    int i1 = geti(x, 2L * n, iw), i2 = geti(x, 2L * n + 1, iw);
    i1 = (i1 >= 0 && i1 < 119) ? i1 : 0;
    i2 = (i2 >= 0 && i2 < 3) ? i2 : 0;
#pragma unroll
    for (int j = 0; j < 5; j++) {
        int f = lane + 64 * j;
        float v = 0.f;
        if (f < EMB) v = b2f(emb1[i1 * EMB + f]) + b2f(emb2[i2 * EMB + f]);
        h[(size_t)n * EMB_P + f] = f2b(v);
    }
}

// ---------------- aggregation: depth-2 pipeline ----------------
__global__ __launch_bounds__(256) void aggregate_kernel(const u16* __restrict__ h,
                                                        u16* __restrict__ aggr,
                                                        const int* __restrict__ offsets,
                                                        const int* __restrict__ csr_src,
                                                        const int* __restrict__ Ccnt,
                                                        const u16* __restrict__ e1,
                                                        const u16* __restrict__ e2) {
    __shared__ float eetab[15 * EMB_P];
    int tid = threadIdx.x;
    for (int idx = tid; idx < 15 * EMB_P; idx += 256) {
        int c = idx / EMB_P, f = idx % EMB_P;
        float v = 0.f;
        if (f < EMB) v = b2f(e1[(c / 3) * EMB + f]) + b2f(e2[(c % 3) * EMB + f]);
        eetab[idx] = v;
    }
    __syncthreads();
    int wave = tid >> 6, lane = tid & 63;
    int n = blockIdx.x * 4 + wave;
    float acc[5];
#pragma unroll
    for (int j = 0; j < 5; j++) acc[j] = b2f(h[(size_t)n * EMB_P + lane + 64 * j]); // self loop
    int e_beg = offsets[n], e_end = offsets[n + 1];
    int cnt = e_end - e_beg;
    if (cnt > 0) {
        int i0 = csr_src[e_beg];
        int i1 = (cnt > 1) ? csr_src[e_beg + 1] : 0;
        int i2 = (cnt > 2) ? csr_src[e_beg + 2] : 0;
        int i3 = (cnt > 3) ? csr_src[e_beg + 3] : 0;
        u16 A_[5], B_[5];
        {
            const u16* r = h + (size_t)i0 * EMB_P + lane;
#pragma unroll
            for (int j = 0; j < 5; j++) A_[j] = r[64 * j];
        }
        if (cnt > 1) {
            const u16* r = h + (size_t)i1 * EMB_P + lane;
#pragma unroll
            for (int j = 0; j < 5; j++) B_[j] = r[64 * j];
        }
        int e = 0;
        for (; e + 3 < cnt; e += 2) {
#pragma unroll
            for (int j = 0; j < 5; j++) acc[j] += b2f(A_[j]);
            {
                const u16* r = h + (size_t)i2 * EMB_P + lane;
#pragma unroll
                for (int j = 0; j < 5; j++) A_[j] = r[64 * j];
            }
#pragma unroll
            for (int j = 0; j < 5; j++) acc[j] += b2f(B_[j]);
            {
                const u16* r = h + (size_t)i3 * EMB_P + lane;
#pragma unroll
                for (int j = 0; j < 5; j++) B_[j] = r[64 * j];
            }
            i2 = (e + 4 < cnt) ? csr_src[e_beg + e + 4] : 0;
            i3 = (e + 5 < cnt) ? csr_src[e_beg + e + 5] : 0;
        }
        if (e < cnt) {
#pragma unroll
            for (int j = 0; j < 5; j++) acc[j] += b2f(A_[j]);
        }
        if (e + 1 < cnt) {
#pragma unroll
            for (int j = 0; j < 5; j++) acc[j] += b2f(B_[j]);
        }
        if (e + 2 < cnt) {
            const u16* r = h + (size_t)i2 * EMB_P + lane;
#pragma unroll
            for (int j = 0; j < 5; j++) acc[j] += b2f(r[64 * j]);
        }
    }
#pragma unroll
    for (int c = 0; c < 15; c++) {
        float cntf = (float)Ccnt[n * 16 + c] + (c == 12 ? 1.0f : 0.0f);
#pragma unroll
        for (int j = 0; j < 5; j++) acc[j] += cntf * eetab[c * EMB_P + lane + 64 * j];
    }
#pragma unroll
    for (int j = 0; j < 5; j++) aggr[(size_t)n * EMB_P + lane + 64 * j] = f2b(acc[j]);
}

// ---------------- 128x128 bf16 MFMA GEMM (head GEMMs, scalar epilogue, fp32 opt) ----------------
__global__ __launch_bounds__(256) void gemm_bf16(const u16* __restrict__ A,
                                                 const u16* __restrict__ Bt,
                                                 const u16* __restrict__ bias,
                                                 u16* __restrict__ Cb,
                                                 float* __restrict__ Cf,
                                                 int K, int lda, int ldb, int ldc,
                                                 int Mstore, int Nstore, int relu) {
    __shared__ u16 As[128 * 64];
    __shared__ u16 Bs[128 * 64];
    int tid = threadIdx.x;
    int lane = tid & 63, wave = tid >> 6;
    int wm = (wave >> 1) * 64, wn = (wave & 1) * 64;
    int n0 = blockIdx.x * 128, m0 = blockIdx.y * 128;
    int q = lane >> 4, r16 = lane & 15;
    int wrow = wave * 32;
    int lcol = (lane & 7) * 8;

    f32x4 acc[4][4];
#pragma unroll
    for (int i = 0; i < 4; i++)
#pragma unroll
        for (int j = 0; j < 4; j++) acc[i][j] = (f32x4){0.f, 0.f, 0.f, 0.f};

    for (int k0 = 0; k0 < K; k0 += 64) {
#pragma unroll
        for (int p = 0; p < 4; p++) {
            gll16(A + (size_t)(m0 + wrow + p * 8 + (lane >> 3)) * lda + k0 + lcol, &As[(wrow + p * 8) * 64]);
            gll16(Bt + (size_t)(n0 + wrow + p * 8 + (lane >> 3)) * ldb + k0 + lcol, &Bs[(wrow + p * 8) * 64]);
        }
        __syncthreads();
#pragma unroll
        for (int kk = 0; kk < 2; kk++) {
            short8 af[4], bfr[4];
#pragma unroll
            for (int i = 0; i < 4; i++)
                af[i] = *(const short8*)(&As[(wm + i * 16 + r16) * 64 + kk * 32 + q * 8]);
#pragma unroll
            for (int j = 0; j < 4; j++)
                bfr[j] = *(const short8*)(&Bs[(wn + j * 16 + r16) * 64 + kk * 32 + q * 8]);
#pragma unroll
            for (int i = 0; i < 4; i++)
#pragma unroll
                for (int j = 0; j < 4; j++)
                    acc[i][j] = __builtin_amdgcn_mfma_f32_16x16x32_bf16(af[i], bfr[j], acc[i][j], 0, 0, 0);
        }
        __syncthreads();
    }
#pragma unroll
    for (int i = 0; i < 4; i++) {
#pragma unroll
        for (int j = 0; j < 4; j++) {
            int n_g = n0 + wn + j * 16 + r16;
            float bv = (n_g < Nstore) ? b2f(bias[n_g]) : 0.f;
#pragma unroll
            for (int rr = 0; rr < 4; rr++) {
                int m_g = m0 + wm + i * 16 + q * 4 + rr;
                if (m_g < Mstore && n_g < Nstore) {
                    float v = acc[i][j][rr] + bv;
                    if (relu) v = fmaxf(v, 0.f);
                    if (Cb) Cb[(size_t)m_g * ldc + n_g] = f2b(v);
                    if (Cf) Cf[(size_t)m_g * ldc + n_g] = v;
                }
            }
        }
    }
}

// ---------------- 128x128 layer GEMM: XCD swizzle + LDS-transpose vector epilogue ----------------
#define CS_W 130
__global__ __launch_bounds__(256) void gemm_layer(const u16* __restrict__ A,
                                                  const u16* __restrict__ Bt,
                                                  const u16* __restrict__ bias,
                                                  u16* __restrict__ C,
                                                  int K, int lda, int ldb, int ldc,
                                                  int mtiles, int ntiles,
                                                  int Nstore, int relu) {
    __shared__ u16 smem[128 * CS_W];
    u16* As = smem;
    u16* Bs = smem + 128 * 64;
    int tid = threadIdx.x;
    int lane = tid & 63, wave = tid >> 6;
    int wm = (wave >> 1) * 64, wn = (wave & 1) * 64;
    int bid = blockIdx.x, mt, nt;
    if ((mtiles & 7) == 0) {
        int xcd = bid & 7, slot = bid >> 3;
        int qm = slot / ntiles;
        mt = xcd + 8 * qm;
        nt = slot - qm * ntiles;
    } else {
        mt = bid / ntiles;
        nt = bid - (bid / ntiles) * ntiles;
    }
    int m0 = mt * 128, n0 = nt * 128;
    int q = lane >> 4, r16 = lane & 15;
    int wrow = wave * 32;
    int lcol = (lane & 7) * 8;

    f32x4 acc[4][4];
#pragma unroll
    for (int i = 0; i < 4; i++)
#pragma unroll
        for (int j = 0; j < 4; j++) acc[i][j] = (f32x4){0.f, 0.f, 0.f, 0.f};

    for (int k0 = 0; k0 < K; k0 += 64) {
#pragma unroll
        for (int p = 0; p < 4; p++) {
            gll16(A + (size_t)(m0 + wrow + p * 8 + (lane >> 3)) * lda + k0 + lcol, &As[(wrow + p * 8) * 64]);
            gll16(Bt + (size_t)(n0 + wrow + p * 8 + (lane >> 3)) * ldb + k0 + lcol, &Bs[(wrow + p * 8) * 64]);
        }
        __syncthreads();
#pragma unroll
        for (int kk = 0; kk < 2; kk++) {
            short8 af[4], bfr[4];
#pragma unroll
            for (int i = 0; i < 4; i++)
                af[i] = *(const short8*)(&As[(wm + i * 16 + r16) * 64 + kk * 32 + q * 8]);
#pragma unroll
            for (int j = 0; j < 4; j++)
                bfr[j] = *(const short8*)(&Bs[(wn + j * 16 + r16) * 64 + kk * 32 + q * 8]);
#pragma unroll
            for (int i = 0; i < 4; i++)
#pragma unroll
                for (int j = 0; j < 4; j++)
                    acc[i][j] = __builtin_amdgcn_mfma_f32_16x16x32_bf16(af[i], bfr[j], acc[i][j], 0, 0, 0);
        }
        __syncthreads();
    }
#pragma unroll
    for (int i = 0; i < 4; i++) {
#pragma unroll
        for (int j = 0; j < 4; j++) {
            int nn = wn + j * 16 + r16;
            float bv = b2f(bias[n0 + nn]);
#pragma unroll
            for (int rr = 0; rr < 4; rr++) {
                float v = acc[i][j][rr] + bv;
                if (relu) v = fmaxf(v, 0.f);
                smem[(wm + i * 16 + q * 4 + rr) * CS_W + nn] = f2b(v);
            }
        }
    }
    __syncthreads();
    int row = tid >> 1, cbase = (tid & 1) * 64;
    if (n0 + cbase < Nstore) {
        u16* dst = C + (size_t)(m0 + row) * ldc + n0 + cbase;
        const u16* src = &smem[row * CS_W + cbase];
#pragma unroll
        for (int k = 0; k < 8; k++)
            *(short8*)(dst + k * 8) = *(const short8*)(src + k * 8);
    }
}

// ---------------- graph boundaries ----------------
__global__ void graph_bounds(const int* __restrict__ batch, int* __restrict__ gstart,
                             const int* __restrict__ flags) {
    int g = blockIdx.x * 256 + threadIdx.x;
    if (g > N_GRAPHS) return;
    int iw = flags[1];
    int lo = 0, hi = N_NODES;
    while (lo < hi) {
        int mid = (lo + hi) >> 1;
        if (geti(batch, mid, iw) < g) lo = mid + 1; else hi = mid;
    }
    gstart[g] = lo;
}

// ---------------- mean pool ----------------
__global__ __launch_bounds__(256) void pool_kernel(const u16* __restrict__ h,
                                                   const int* __restrict__ gstart,
                                                   u16* __restrict__ hgp) {
    int wave = threadIdx.x >> 6, lane = threadIdx.x & 63;
    int g = blockIdx.x * 4 + wave;
    int s = gstart[g], e = gstart[g + 1];
    float acc[5] = {0.f, 0.f, 0.f, 0.f, 0.f};
    for (int n = s; n < e; n++) {
        const u16* hp = h + (size_t)n * EMB_P + lane;
#pragma unroll
        for (int j = 0; j < 5; j++) acc[j] += b2f(hp[64 * j]);
    }
    int cnt = e - s;
    float inv = 1.0f / (float)(cnt > 1 ? cnt : 1);
#pragma unroll
    for (int j = 0; j < 5; j++) hgp[(size_t)g * EMB_P + lane + 64 * j] = f2b(acc[j] * inv);
}

extern "C" void kernel_launch(void* const* d_in, const int* in_sizes, int n_in,
                              void* d_out, int out_size, void* d_ws, size_t ws_size,
                              hipStream_t stream) {
    const int* x       = (const int*)d_in[0];
    const int* ei      = (const int*)d_in[1];
    const int* ea      = (const int*)d_in[2];
    const int* batch   = (const int*)d_in[3];
    float* out = (float*)d_out;   // fp32 output (established round 6)

    char* wp = (char*)d_ws;
    auto alloc = [&](size_t bytes) -> void* {
        void* r = (void*)wp;
        wp += (bytes + 255) & ~(size_t)255;
        return r;
    };
    int* flags   = (int*)alloc(16 * 4);
    int* gstart  = (int*)alloc((N_GRAPHS + 1) * 4);
    int* deg     = (int*)alloc(N_NODES * 4);
    int* cursor  = (int*)alloc(N_NODES * 4);
    int* offsets = (int*)alloc((N_NODES + 1) * 4);
    u16* cbuf    = (u16*)alloc((size_t)CVT_TOTAL * 2);
    u16* wbuf    = (u16*)alloc((size_t)W_TOTAL * 2);
    u16* hg_pre  = (u16*)alloc((size_t)G_P * EMB_P * 2);
    u16* hgbuf   = (u16*)alloc((size_t)G_P * FEAT * 2);
    u16* pbuf0   = (u16*)alloc((size_t)G_P * OUTD * 2);
    u16* pbuf1   = (u16*)alloc((size_t)G_P * OUTD * 2);
    int* csr_src = (int*)alloc(N_EDGES * 4);
    int* Ccnt    = (int*)alloc((size_t)N_NODES * 16 * 4);
    u16* aggr    = (u16*)alloc((size_t)M_P * EMB_P * 2);
    u16* h       = (u16*)alloc((size_t)M_P * EMB_P * 2);

    size_t used = (size_t)(wp - (char*)d_ws);
    size_t remain = (ws_size > used) ? (ws_size - used - 4096) : 0;
    size_t hdnFull = (size_t)M_P * HID_P * 2;
    int nstrip = 8;
    if (remain >= hdnFull)          nstrip = 1;
    else if (remain >= hdnFull / 2) nstrip = 2;
    else if (remain >= hdnFull / 4) nstrip = 4;
    int stripRows = M_P / nstrip;
    u16* hdn = (u16*)alloc(hdnFull / nstrip);

    detect_kernel<<<1, 256, 0, stream>>>(d_in[4], ei, flags);
    CvtArgs ca;
    for (int i = 0; i < 16; i++) ca.src[i] = d_in[4 + i];
    cvt_all<<<(CVT_TOTAL + 255) / 256, 256, 0, stream>>>(ca, cbuf, flags);
    tpad_all<<<(W_TOTAL + 255) / 256, 256, 0, stream>>>(cbuf, wbuf);

    const u16* x_emb1  = cbuf + OFF_EMB1;
    const u16* x_emb2  = cbuf + OFF_EMB2;
    const u16* edge_e1 = cbuf + OFF_E1;
    const u16* edge_e2 = cbuf + OFF_E2;
    const u16* fb      = cbuf + OFF_FB;
    const u16* p0b     = cbuf + OFF_P0B;
    const u16* p1b     = cbuf + OFF_P1B;
    const u16* p2b     = cbuf + OFF_P2B;
    const u16* W1t     = wbuf + WOFF_W1T;
    const u16* W2t     = wbuf + WOFF_W2T;
    const u16* featWt  = wbuf + WOFF_FWT;
    const u16* p0Wt    = wbuf + WOFF_P0T;
    const u16* p1Wt    = wbuf + WOFF_P1T;
    const u16* p2Wt    = wbuf + WOFF_P2T;
    const u16* b1p     = wbuf + WOFF_B1P;
    const u16* b2p     = wbuf + WOFF_B2P;

    hipMemsetAsync(deg, 0, N_NODES * 4, stream);
    hipMemsetAsync(Ccnt, 0, (size_t)N_NODES * 16 * 4, stream);

    count_edges<<<(N_EDGES + 255) / 256, 256, 0, stream>>>(ei, ea, deg, Ccnt, flags);
    scan50k<<<1, 1024, 0, stream>>>(deg, offsets, cursor);
    fill_csr<<<(N_EDGES + 255) / 256, 256, 0, stream>>>(ei, cursor, csr_src, flags);
    sort_csr<<<(N_NODES + 255) / 256, 256, 0, stream>>>(offsets, csr_src);
    graph_bounds<<<(N_GRAPHS + 1 + 255) / 256, 256, 0, stream>>>(batch, gstart, flags);

    embed_kernel<<<N_NODES / 4, 256, 0, stream>>>(x, x_emb1, x_emb2, h, flags);

    for (int l = 0; l < NLAYER; l++) {
        aggregate_kernel<<<N_NODES / 4, 256, 0, stream>>>(
            h, aggr, offsets, csr_src, Ccnt,
            edge_e1 + (size_t)l * 5 * EMB, edge_e2 + (size_t)l * 3 * EMB);
        int mtilesS = stripRows / 128;
        for (int s = 0; s < nstrip; s++) {
            size_t r0 = (size_t)s * stripRows;
            gemm_layer<<<mtilesS * (HID_P / 128), 256, 0, stream>>>(
                aggr + r0 * EMB_P, W1t + (size_t)l * HID_P * EMB_P,
                b1p + (size_t)l * HID_P, hdn,
                EMB_P, EMB_P, EMB_P, HID_P, mtilesS, HID_P / 128, HID_P, 1);
            gemm_layer<<<mtilesS * (NP2 / 128), 256, 0, stream>>>(
                hdn, W2t + (size_t)l * NP2 * HID_P,
                b2p + (size_t)l * NP2, h + r0 * EMB_P,
                HID_P, HID_P, HID_P, EMB_P, mtilesS, NP2 / 128, EMB_P, (l < NLAYER - 1) ? 1 : 0);
        }
    }

    pool_kernel<<<N_GRAPHS / 4, 256, 0, stream>>>(h, gstart, hg_pre);

    gemm_bf16<<<dim3(FEAT / 128, G_P / 128), 256, 0, stream>>>(
        hg_pre, featWt, fb, hgbuf, out,
        EMB_P, EMB_P, EMB_P, FEAT, N_GRAPHS, FEAT, 0);
    gemm_bf16<<<dim3(OUTD / 128, G_P / 128), 256, 0, stream>>>(
        hgbuf, p0Wt, p0b, pbuf0, nullptr,
        FEAT, FEAT, FEAT, OUTD, N_GRAPHS, OUTD, 1);
    gemm_bf16<<<dim3(OUTD / 128, G_P / 128), 256, 0, stream>>>(
        pbuf0, p1Wt, p1b, pbuf1, nullptr,
        OUTD, OUTD, OUTD, OUTD, N_GRAPHS, OUTD, 1);
    gemm_bf16<<<dim3(OUTD / 128, G_P / 128), 256, 0, stream>>>(
        pbuf1, p2Wt, p2b, nullptr, out + (size_t)N_GRAPHS * FEAT,
        OUTD, OUTD, OUTD, OUTD, N_GRAPHS, OUTD, 0);
}

// Round 14
// 1395.514 us; speedup vs baseline: 1.1190x; 1.1190x over previous
//
#include <hip/hip_runtime.h>
#include <stdint.h>
#include <stddef.h>

typedef unsigned short u16;
typedef __attribute__((ext_vector_type(8))) short short8;
typedef __attribute__((ext_vector_type(4))) float f32x4;

#define N_NODES 50000
#define N_EDGES 800000
#define N_GRAPHS 2000
#define EMB 300
#define EMB_P 320
#define HID 600
#define HID_P 640
#define NP2 384
#define M_P 50176
#define G_P 2048
#define FEAT 512
#define OUTD 256
#define NLAYER 5
#define SCAN_BLOCKS ((N_NODES + 255) / 256)   // 196

// ---- bf16 cvt arena offsets ----
#define OFF_EMB1 0
#define N_EMB1   (119 * EMB)
#define OFF_EMB2 (OFF_EMB1 + N_EMB1)
#define N_EMB2   (3 * EMB)
#define OFF_E1   (OFF_EMB2 + N_EMB2)
#define N_E1     (NLAYER * 5 * EMB)
#define OFF_E2   (OFF_E1 + N_E1)
#define N_E2     (NLAYER * 3 * EMB)
#define OFF_W1   (OFF_E2 + N_E2)
#define N_W1     (NLAYER * EMB * HID)
#define OFF_B1   (OFF_W1 + N_W1)
#define N_B1     (NLAYER * HID)
#define OFF_W2   (OFF_B1 + N_B1)
#define N_W2     (NLAYER * HID * EMB)
#define OFF_B2   (OFF_W2 + N_W2)
#define N_B2     (NLAYER * EMB)
#define OFF_FW   (OFF_B2 + N_B2)
#define N_FW     (EMB * FEAT)
#define OFF_FB   (OFF_FW + N_FW)
#define N_FB     (FEAT)
#define OFF_P0W  (OFF_FB + N_FB)
#define N_P0W    (FEAT * (FEAT / 2))
#define OFF_P0B  (OFF_P0W + N_P0W)
#define N_P0B    (FEAT / 2)
#define OFF_P1W  (OFF_P0B + N_P0B)
#define N_P1W    ((FEAT / 2) * (FEAT / 2))
#define OFF_P1B  (OFF_P1W + N_P1W)
#define N_P1B    (FEAT / 2)
#define OFF_P2W  (OFF_P1B + N_P1B)
#define N_P2W    ((FEAT / 2) * OUTD)
#define OFF_P2B  (OFF_P2W + N_P2W)
#define N_P2B    (OUTD)
#define CVT_TOTAL (OFF_P2B + N_P2B)

// ---- transposed-weight arena offsets ----
#define WOFF_W1T 0
#define WN_W1T   (NLAYER * HID_P * EMB_P)
#define WOFF_W2T (WOFF_W1T + WN_W1T)
#define WN_W2T   (NLAYER * NP2 * HID_P)
#define WOFF_FWT (WOFF_W2T + WN_W2T)
#define WN_FWT   (FEAT * EMB_P)
#define WOFF_P0T (WOFF_FWT + WN_FWT)
#define WN_P0T   (OUTD * FEAT)
#define WOFF_P1T (WOFF_P0T + WN_P0T)
#define WN_P1T   (OUTD * OUTD)
#define WOFF_P2T (WOFF_P1T + WN_P1T)
#define WN_P2T   (OUTD * OUTD)
#define WOFF_B1P (WOFF_P2T + WN_P2T)
#define WN_B1P   (NLAYER * HID_P)
#define WOFF_B2P (WOFF_B1P + WN_B1P)
#define WN_B2P   (NLAYER * NP2)
#define W_TOTAL  (WOFF_B2P + WN_B2P)

__device__ __forceinline__ float b2f(u16 u) {
    union { unsigned int i; float f; } c; c.i = ((unsigned int)u) << 16; return c.f;
}
__device__ __forceinline__ u16 f2b(float f) {
    union { float f; unsigned int i; } c; c.f = f;
    unsigned int x = c.i;
    unsigned int lsb = (x >> 16) & 1u;
    x += 0x7fffu + lsb;
    return (u16)(x >> 16);
}
__device__ __forceinline__ int geti(const int* __restrict__ p, long k, int iw) {
    return p[k << iw];
}
__device__ __forceinline__ void gll16(const u16* g, u16* l) {
    __builtin_amdgcn_global_load_lds((const __attribute__((address_space(1))) void*)g,
                                     (__attribute__((address_space(3))) void*)l, 16, 0, 0);
}

// ---------------- dtype detection ----------------
__global__ __launch_bounds__(256) void detect_kernel(const void* __restrict__ emb1_raw,
                                                     const int* __restrict__ ei_raw,
                                                     int* __restrict__ flags) {
    __shared__ int cnt_s;
    __shared__ int nz_s;
    int tid = threadIdx.x;
    if (tid == 0) { cnt_s = 0; nz_s = 0; }
    __syncthreads();
    const u16* u = (const u16*)emb1_raw;
    int local = 0;
#pragma unroll
    for (int j = 0; j < 8; j++) {
        u16 w = u[2 * (tid * 8 + j)];
        int e = (w >> 7) & 0xFF;
        if (w == 0 || (e >= 90 && e <= 130)) local++;
    }
    atomicAdd(&cnt_s, local);
    int v = ei_raw[2 * tid + 1];
    if (v != 0) atomicOr(&nz_s, 1);
    __syncthreads();
    if (tid == 0) {
        flags[0] = (cnt_s < 1600) ? 1 : 0;
        flags[1] = nz_s ? 0 : 1;
    }
}

// ---------------- convert float params to bf16 arena ----------------
struct CvtArgs { const void* src[16]; };
__constant__ int cvt_off[17] = {OFF_EMB1, OFF_EMB2, OFF_E1, OFF_E2, OFF_W1, OFF_B1,
                                OFF_W2, OFF_B2, OFF_FW, OFF_FB, OFF_P0W, OFF_P0B,
                                OFF_P1W, OFF_P1B, OFF_P2W, OFF_P2B, CVT_TOTAL};

__global__ __launch_bounds__(256) void cvt_all(CvtArgs args, u16* __restrict__ dst,
                                               const int* __restrict__ flags) {
    int idx = blockIdx.x * 256 + threadIdx.x;
    if (idx >= CVT_TOTAL) return;
    int fp32 = flags[0];
    int t = 0;
#pragma unroll
    for (int i = 0; i < 16; i++) {
        if (idx >= cvt_off[i + 1]) t = i + 1;
    }
    int off = idx - cvt_off[t];
    u16 v;
    if (fp32) v = f2b(((const float*)args.src[t])[off]);
    else      v = ((const u16*)args.src[t])[off];
    dst[idx] = v;
}

// ---------------- combined weight transpose+pad ----------------
struct WSeg { int srcOff, Kin, Nin, Kd, Nd, bias; };
__constant__ int wseg_cum[9] = {WOFF_W1T, WOFF_W2T, WOFF_FWT, WOFF_P0T, WOFF_P1T,
                                WOFF_P2T, WOFF_B1P, WOFF_B2P, W_TOTAL};
__constant__ WSeg wsegs[8] = {
    {OFF_W1,  EMB, HID,  EMB_P, HID_P, 0},
    {OFF_W2,  HID, EMB,  HID_P, NP2,   0},
    {OFF_FW,  EMB, FEAT, EMB_P, FEAT,  0},
    {OFF_P0W, FEAT, OUTD, FEAT, OUTD,  0},
    {OFF_P1W, OUTD, OUTD, OUTD, OUTD,  0},
    {OFF_P2W, OUTD, OUTD, OUTD, OUTD,  0},
    {OFF_B1,  HID, 0, 0, HID_P, 1},
    {OFF_B2,  EMB, 0, 0, NP2,   1},
};

__global__ __launch_bounds__(256) void tpad_all(const u16* __restrict__ cbuf,
                                                u16* __restrict__ wbuf) {
    int idx = blockIdx.x * 256 + threadIdx.x;
    if (idx >= W_TOTAL) return;
    int t = 0;
#pragma unroll
    for (int i = 0; i < 8; i++) {
        if (idx >= wseg_cum[i + 1]) t = i + 1;
    }
    WSeg sg = wsegs[t];
    int i = idx - wseg_cum[t];
    u16 v = 0;
    if (sg.bias) {
        int n = i % sg.Nd, l = i / sg.Nd;
        if (n < sg.Kin) v = cbuf[sg.srcOff + l * sg.Kin + n];
    } else {
        int k = i % sg.Kd;
        int r = i / sg.Kd;
        int n = r % sg.Nd, l = r / sg.Nd;
        if (k < sg.Kin && n < sg.Nin) v = cbuf[sg.srcOff + ((long)l * sg.Kin + k) * sg.Nin + n];
    }
    wbuf[idx] = v;
}

// ---------------- CSR build ----------------
__global__ void count_edges(const int* __restrict__ ei, const int* __restrict__ ea,
                            int* __restrict__ deg, int* __restrict__ Ccnt,
                            const int* __restrict__ flags) {
    int e = blockIdx.x * 256 + threadIdx.x;
    if (e >= N_EDGES) return;
    int iw = flags[1];
    int dst = geti(ei, (long)N_EDGES + e, iw);
    if (dst >= 0 && dst < N_NODES) atomicAdd(&deg[dst], 1);
    int a = geti(ea, 2L * e, iw), b = geti(ea, 2L * e + 1, iw);
    if (dst >= 0 && dst < N_NODES && a >= 0 && a < 3 && b >= 0 && b < 3)
        atomicAdd(&Ccnt[dst * 16 + a * 3 + b], 1);
}

// ---- 3-stage parallel exclusive scan of deg[] (replaces single-block scan50k) ----
__global__ __launch_bounds__(256) void scan_s1(const int* __restrict__ deg,
                                               int* __restrict__ locx,
                                               int* __restrict__ bsum) {
    __shared__ int buf[256];
    int b = blockIdx.x, tid = threadIdx.x;
    int i = b * 256 + tid;
    int v = (i < N_NODES) ? deg[i] : 0;
    buf[tid] = v;
    __syncthreads();
#pragma unroll
    for (int off = 1; off < 256; off <<= 1) {
        int t = (tid >= off) ? buf[tid - off] : 0;
        __syncthreads();
        buf[tid] += t;
        __syncthreads();
    }
    if (i < N_NODES) locx[i] = buf[tid] - v;        // exclusive within block
    if (tid == 255) bsum[b] = buf[255];
}

__global__ __launch_bounds__(256) void scan_s2(int* __restrict__ bsum,
                                               int* __restrict__ bpre) {
    __shared__ int buf[256];
    int tid = threadIdx.x;
    int v = (tid < SCAN_BLOCKS) ? bsum[tid] : 0;
    buf[tid] = v;
    __syncthreads();
#pragma unroll
    for (int off = 1; off < 256; off <<= 1) {
        int t = (tid >= off) ? buf[tid - off] : 0;
        __syncthreads();
        buf[tid] += t;
        __syncthreads();
    }
    if (tid < SCAN_BLOCKS) bpre[tid] = buf[tid] - v;  // exclusive
}

__global__ __launch_bounds__(256) void scan_s3(const int* __restrict__ deg,
                                               const int* __restrict__ locx,
                                               const int* __restrict__ bpre,
                                               int* __restrict__ offsets,
                                               int* __restrict__ cursor) {
    int i = blockIdx.x * 256 + threadIdx.x;
    if (i >= N_NODES) return;
    int ex = locx[i] + bpre[blockIdx.x];
    cursor[i] = ex;
    offsets[i + 1] = ex + deg[i];
    if (i == 0) offsets[0] = 0;
}

__global__ void fill_csr(const int* __restrict__ ei, int* __restrict__ cursor,
                         int* __restrict__ csr_src, const int* __restrict__ flags) {
    int e = blockIdx.x * 256 + threadIdx.x;
    if (e >= N_EDGES) return;
    int iw = flags[1];
    int src = geti(ei, (long)e, iw);
    int dst = geti(ei, (long)N_EDGES + e, iw);
    if (dst < 0 || dst >= N_NODES) return;
    int pos = atomicAdd(&cursor[dst], 1);
    if (pos >= 0 && pos < N_EDGES) csr_src[pos] = src;
}

// ---------------- initial embedding ----------------
__global__ __launch_bounds__(256) void embed_kernel(const int* __restrict__ x,
                                                    const u16* __restrict__ emb1,
                                                    const u16* __restrict__ emb2,
                                                    u16* __restrict__ h,
                                                    const int* __restrict__ flags) {
    int wave = threadIdx.x >> 6, lane = threadIdx.x & 63;
    int n = blockIdx.x * 4 + wave;
    int iw = flags[1];
    int i1 = geti(x, 2L * n, iw), i2 = geti(x, 2L * n + 1, iw);
    i1 = (i1 >= 0 && i1 < 119) ? i1 : 0;
    i2 = (i2 >= 0 && i2 < 3) ? i2 : 0;
#pragma unroll
    for (int j = 0; j < 5; j++) {
        int f = lane + 64 * j;
        float v = 0.f;
        if (f < EMB) v = b2f(emb1[i1 * EMB + f]) + b2f(emb2[i2 * EMB + f]);
        h[(size_t)n * EMB_P + f] = f2b(v);
    }
}

// ---------------- aggregation: depth-2 pipeline ----------------
__global__ __launch_bounds__(256) void aggregate_kernel(const u16* __restrict__ h,
                                                        u16* __restrict__ aggr,
                                                        const int* __restrict__ offsets,
                                                        const int* __restrict__ csr_src,
                                                        const int* __restrict__ Ccnt,
                                                        const u16* __restrict__ e1,
                                                        const u16* __restrict__ e2) {
    __shared__ float eetab[15 * EMB_P];
    int tid = threadIdx.x;
    for (int idx = tid; idx < 15 * EMB_P; idx += 256) {
        int c = idx / EMB_P, f = idx % EMB_P;
        float v = 0.f;
        if (f < EMB) v = b2f(e1[(c / 3) * EMB + f]) + b2f(e2[(c % 3) * EMB + f]);
        eetab[idx] = v;
    }
    __syncthreads();
    int wave = tid >> 6, lane = tid & 63;
    int n = blockIdx.x * 4 + wave;
    float acc[5];
#pragma unroll
    for (int j = 0; j < 5; j++) acc[j] = b2f(h[(size_t)n * EMB_P + lane + 64 * j]); // self loop
    int e_beg = offsets[n], e_end = offsets[n + 1];
    int cnt = e_end - e_beg;
    if (cnt > 0) {
        int i0 = csr_src[e_beg];
        int i1 = (cnt > 1) ? csr_src[e_beg + 1] : 0;
        int i2 = (cnt > 2) ? csr_src[e_beg + 2] : 0;
        int i3 = (cnt > 3) ? csr_src[e_beg + 3] : 0;
        u16 A_[5], B_[5];
        {
            const u16* r = h + (size_t)i0 * EMB_P + lane;
#pragma unroll
            for (int j = 0; j < 5; j++) A_[j] = r[64 * j];
        }
        if (cnt > 1) {
            const u16* r = h + (size_t)i1 * EMB_P + lane;
#pragma unroll
            for (int j = 0; j < 5; j++) B_[j] = r[64 * j];
        }
        int e = 0;
        for (; e + 3 < cnt; e += 2) {
#pragma unroll
            for (int j = 0; j < 5; j++) acc[j] += b2f(A_[j]);
            {
                const u16* r = h + (size_t)i2 * EMB_P + lane;
#pragma unroll
                for (int j = 0; j < 5; j++) A_[j] = r[64 * j];
            }
#pragma unroll
            for (int j = 0; j < 5; j++) acc[j] += b2f(B_[j]);
            {
                const u16* r = h + (size_t)i3 * EMB_P + lane;
#pragma unroll
                for (int j = 0; j < 5; j++) B_[j] = r[64 * j];
            }
            i2 = (e + 4 < cnt) ? csr_src[e_beg + e + 4] : 0;
            i3 = (e + 5 < cnt) ? csr_src[e_beg + e + 5] : 0;
        }
        if (e < cnt) {
#pragma unroll
            for (int j = 0; j < 5; j++) acc[j] += b2f(A_[j]);
        }
        if (e + 1 < cnt) {
#pragma unroll
            for (int j = 0; j < 5; j++) acc[j] += b2f(B_[j]);
        }
        if (e + 2 < cnt) {
            const u16* r = h + (size_t)i2 * EMB_P + lane;
#pragma unroll
            for (int j = 0; j < 5; j++) acc[j] += b2f(r[64 * j]);
        }
    }
#pragma unroll
    for (int c = 0; c < 15; c++) {
        float cntf = (float)Ccnt[n * 16 + c] + (c == 12 ? 1.0f : 0.0f);
#pragma unroll
        for (int j = 0; j < 5; j++) acc[j] += cntf * eetab[c * EMB_P + lane + 64 * j];
    }
#pragma unroll
    for (int j = 0; j < 5; j++) aggr[(size_t)n * EMB_P + lane + 64 * j] = f2b(acc[j]);
}

// ---------------- 128x128 bf16 MFMA GEMM (head GEMMs, scalar epilogue, fp32 opt) ----------------
__global__ __launch_bounds__(256) void gemm_bf16(const u16* __restrict__ A,
                                                 const u16* __restrict__ Bt,
                                                 const u16* __restrict__ bias,
                                                 u16* __restrict__ Cb,
                                                 float* __restrict__ Cf,
                                                 int K, int lda, int ldb, int ldc,
                                                 int Mstore, int Nstore, int relu) {
    __shared__ u16 As[128 * 64];
    __shared__ u16 Bs[128 * 64];
    int tid = threadIdx.x;
    int lane = tid & 63, wave = tid >> 6;
    int wm = (wave >> 1) * 64, wn = (wave & 1) * 64;
    int n0 = blockIdx.x * 128, m0 = blockIdx.y * 128;
    int q = lane >> 4, r16 = lane & 15;
    int wrow = wave * 32;
    int lcol = (lane & 7) * 8;

    f32x4 acc[4][4];
#pragma unroll
    for (int i = 0; i < 4; i++)
#pragma unroll
        for (int j = 0; j < 4; j++) acc[i][j] = (f32x4){0.f, 0.f, 0.f, 0.f};

    for (int k0 = 0; k0 < K; k0 += 64) {
#pragma unroll
        for (int p = 0; p < 4; p++) {
            gll16(A + (size_t)(m0 + wrow + p * 8 + (lane >> 3)) * lda + k0 + lcol, &As[(wrow + p * 8) * 64]);
            gll16(Bt + (size_t)(n0 + wrow + p * 8 + (lane >> 3)) * ldb + k0 + lcol, &Bs[(wrow + p * 8) * 64]);
        }
        __syncthreads();
#pragma unroll
        for (int kk = 0; kk < 2; kk++) {
            short8 af[4], bfr[4];
#pragma unroll
            for (int i = 0; i < 4; i++)
                af[i] = *(const short8*)(&As[(wm + i * 16 + r16) * 64 + kk * 32 + q * 8]);
#pragma unroll
            for (int j = 0; j < 4; j++)
                bfr[j] = *(const short8*)(&Bs[(wn + j * 16 + r16) * 64 + kk * 32 + q * 8]);
#pragma unroll
            for (int i = 0; i < 4; i++)
#pragma unroll
                for (int j = 0; j < 4; j++)
                    acc[i][j] = __builtin_amdgcn_mfma_f32_16x16x32_bf16(af[i], bfr[j], acc[i][j], 0, 0, 0);
        }
        __syncthreads();
    }
#pragma unroll
    for (int i = 0; i < 4; i++) {
#pragma unroll
        for (int j = 0; j < 4; j++) {
            int n_g = n0 + wn + j * 16 + r16;
            float bv = (n_g < Nstore) ? b2f(bias[n_g]) : 0.f;
#pragma unroll
            for (int rr = 0; rr < 4; rr++) {
                int m_g = m0 + wm + i * 16 + q * 4 + rr;
                if (m_g < Mstore && n_g < Nstore) {
                    float v = acc[i][j][rr] + bv;
                    if (relu) v = fmaxf(v, 0.f);
                    if (Cb) Cb[(size_t)m_g * ldc + n_g] = f2b(v);
                    if (Cf) Cf[(size_t)m_g * ldc + n_g] = v;
                }
            }
        }
    }
}

// ---------------- 128x128 layer GEMM: XCD swizzle + LDS-transpose vector epilogue ----------------
#define CS_W 130
__global__ __launch_bounds__(256) void gemm_layer(const u16* __restrict__ A,
                                                  const u16* __restrict__ Bt,
                                                  const u16* __restrict__ bias,
                                                  u16* __restrict__ C,
                                                  int K, int lda, int ldb, int ldc,
                                                  int mtiles, int ntiles,
                                                  int Nstore, int relu) {
    __shared__ u16 smem[128 * CS_W];
    u16* As = smem;
    u16* Bs = smem + 128 * 64;
    int tid = threadIdx.x;
    int lane = tid & 63, wave = tid >> 6;
    int wm = (wave >> 1) * 64, wn = (wave & 1) * 64;
    int bid = blockIdx.x, mt, nt;
    if ((mtiles & 7) == 0) {
        int xcd = bid & 7, slot = bid >> 3;
        int qm = slot / ntiles;
        mt = xcd + 8 * qm;
        nt = slot - qm * ntiles;
    } else {
        mt = bid / ntiles;
        nt = bid - (bid / ntiles) * ntiles;
    }
    int m0 = mt * 128, n0 = nt * 128;
    int q = lane >> 4, r16 = lane & 15;
    int wrow = wave * 32;
    int lcol = (lane & 7) * 8;

    f32x4 acc[4][4];
#pragma unroll
    for (int i = 0; i < 4; i++)
#pragma unroll
        for (int j = 0; j < 4; j++) acc[i][j] = (f32x4){0.f, 0.f, 0.f, 0.f};

    for (int k0 = 0; k0 < K; k0 += 64) {
#pragma unroll
        for (int p = 0; p < 4; p++) {
            gll16(A + (size_t)(m0 + wrow + p * 8 + (lane >> 3)) * lda + k0 + lcol, &As[(wrow + p * 8) * 64]);
            gll16(Bt + (size_t)(n0 + wrow + p * 8 + (lane >> 3)) * ldb + k0 + lcol, &Bs[(wrow + p * 8) * 64]);
        }
        __syncthreads();
#pragma unroll
        for (int kk = 0; kk < 2; kk++) {
            short8 af[4], bfr[4];
#pragma unroll
            for (int i = 0; i < 4; i++)
                af[i] = *(const short8*)(&As[(wm + i * 16 + r16) * 64 + kk * 32 + q * 8]);
#pragma unroll
            for (int j = 0; j < 4; j++)
                bfr[j] = *(const short8*)(&Bs[(wn + j * 16 + r16) * 64 + kk * 32 + q * 8]);
#pragma unroll
            for (int i = 0; i < 4; i++)
#pragma unroll
                for (int j = 0; j < 4; j++)
                    acc[i][j] = __builtin_amdgcn_mfma_f32_16x16x32_bf16(af[i], bfr[j], acc[i][j], 0, 0, 0);
        }
        __syncthreads();
    }
#pragma unroll
    for (int i = 0; i < 4; i++) {
#pragma unroll
        for (int j = 0; j < 4; j++) {
            int nn = wn + j * 16 + r16;
            float bv = b2f(bias[n0 + nn]);
#pragma unroll
            for (int rr = 0; rr < 4; rr++) {
                float v = acc[i][j][rr] + bv;
                if (relu) v = fmaxf(v, 0.f);
                smem[(wm + i * 16 + q * 4 + rr) * CS_W + nn] = f2b(v);
            }
        }
    }
    __syncthreads();
    int row = tid >> 1, cbase = (tid & 1) * 64;
    if (n0 + cbase < Nstore) {
        u16* dst = C + (size_t)(m0 + row) * ldc + n0 + cbase;
        const u16* src = &smem[row * CS_W + cbase];
#pragma unroll
        for (int k = 0; k < 8; k++)
            *(short8*)(dst + k * 8) = *(const short8*)(src + k * 8);
    }
}

// ---------------- graph boundaries ----------------
__global__ void graph_bounds(const int* __restrict__ batch, int* __restrict__ gstart,
                             const int* __restrict__ flags) {
    int g = blockIdx.x * 256 + threadIdx.x;
    if (g > N_GRAPHS) return;
    int iw = flags[1];
    int lo = 0, hi = N_NODES;
    while (lo < hi) {
        int mid = (lo + hi) >> 1;
        if (geti(batch, mid, iw) < g) lo = mid + 1; else hi = mid;
    }
    gstart[g] = lo;
}

// ---------------- mean pool ----------------
__global__ __launch_bounds__(256) void pool_kernel(const u16* __restrict__ h,
                                                   const int* __restrict__ gstart,
                                                   u16* __restrict__ hgp) {
    int wave = threadIdx.x >> 6, lane = threadIdx.x & 63;
    int g = blockIdx.x * 4 + wave;
    int s = gstart[g], e = gstart[g + 1];
    float acc[5] = {0.f, 0.f, 0.f, 0.f, 0.f};
    for (int n = s; n < e; n++) {
        const u16* hp = h + (size_t)n * EMB_P + lane;
#pragma unroll
        for (int j = 0; j < 5; j++) acc[j] += b2f(hp[64 * j]);
    }
    int cnt = e - s;
    float inv = 1.0f / (float)(cnt > 1 ? cnt : 1);
#pragma unroll
    for (int j = 0; j < 5; j++) hgp[(size_t)g * EMB_P + lane + 64 * j] = f2b(acc[j] * inv);
}

extern "C" void kernel_launch(void* const* d_in, const int* in_sizes, int n_in,
                              void* d_out, int out_size, void* d_ws, size_t ws_size,
                              hipStream_t stream) {
    const int* x       = (const int*)d_in[0];
    const int* ei      = (const int*)d_in[1];
    const int* ea      = (const int*)d_in[2];
    const int* batch   = (const int*)d_in[3];
    float* out = (float*)d_out;   // fp32 output (established round 6)

    char* wp = (char*)d_ws;
    auto alloc = [&](size_t bytes) -> void* {
        void* r = (void*)wp;
        wp += (bytes + 255) & ~(size_t)255;
        return r;
    };
    int* flags   = (int*)alloc(16 * 4);
    int* gstart  = (int*)alloc((N_GRAPHS + 1) * 4);
    int* deg     = (int*)alloc(N_NODES * 4);
    int* cursor  = (int*)alloc(N_NODES * 4);
    int* offsets = (int*)alloc((N_NODES + 1) * 4);
    int* locx    = (int*)alloc(N_NODES * 4);
    int* bsum    = (int*)alloc(256 * 4);
    int* bpre    = (int*)alloc(256 * 4);
    u16* cbuf    = (u16*)alloc((size_t)CVT_TOTAL * 2);
    u16* wbuf    = (u16*)alloc((size_t)W_TOTAL * 2);
    u16* hg_pre  = (u16*)alloc((size_t)G_P * EMB_P * 2);
    u16* hgbuf   = (u16*)alloc((size_t)G_P * FEAT * 2);
    u16* pbuf0   = (u16*)alloc((size_t)G_P * OUTD * 2);
    u16* pbuf1   = (u16*)alloc((size_t)G_P * OUTD * 2);
    int* csr_src = (int*)alloc(N_EDGES * 4);
    int* Ccnt    = (int*)alloc((size_t)N_NODES * 16 * 4);
    u16* aggr    = (u16*)alloc((size_t)M_P * EMB_P * 2);
    u16* h       = (u16*)alloc((size_t)M_P * EMB_P * 2);

    size_t used = (size_t)(wp - (char*)d_ws);
    size_t remain = (ws_size > used) ? (ws_size - used - 4096) : 0;
    size_t hdnFull = (size_t)M_P * HID_P * 2;
    int nstrip = 8;
    if (remain >= hdnFull)          nstrip = 1;
    else if (remain >= hdnFull / 2) nstrip = 2;
    else if (remain >= hdnFull / 4) nstrip = 4;
    int stripRows = M_P / nstrip;
    u16* hdn = (u16*)alloc(hdnFull / nstrip);

    detect_kernel<<<1, 256, 0, stream>>>(d_in[4], ei, flags);
    CvtArgs ca;
    for (int i = 0; i < 16; i++) ca.src[i] = d_in[4 + i];
    cvt_all<<<(CVT_TOTAL + 255) / 256, 256, 0, stream>>>(ca, cbuf, flags);
    tpad_all<<<(W_TOTAL + 255) / 256, 256, 0, stream>>>(cbuf, wbuf);

    const u16* x_emb1  = cbuf + OFF_EMB1;
    const u16* x_emb2  = cbuf + OFF_EMB2;
    const u16* edge_e1 = cbuf + OFF_E1;
    const u16* edge_e2 = cbuf + OFF_E2;
    const u16* fb      = cbuf + OFF_FB;
    const u16* p0b     = cbuf + OFF_P0B;
    const u16* p1b     = cbuf + OFF_P1B;
    const u16* p2b     = cbuf + OFF_P2B;
    const u16* W1t     = wbuf + WOFF_W1T;
    const u16* W2t     = wbuf + WOFF_W2T;
    const u16* featWt  = wbuf + WOFF_FWT;
    const u16* p0Wt    = wbuf + WOFF_P0T;
    const u16* p1Wt    = wbuf + WOFF_P1T;
    const u16* p2Wt    = wbuf + WOFF_P2T;
    const u16* b1p     = wbuf + WOFF_B1P;
    const u16* b2p     = wbuf + WOFF_B2P;

    hipMemsetAsync(deg, 0, N_NODES * 4, stream);
    hipMemsetAsync(Ccnt, 0, (size_t)N_NODES * 16 * 4, stream);

    count_edges<<<(N_EDGES + 255) / 256, 256, 0, stream>>>(ei, ea, deg, Ccnt, flags);
    scan_s1<<<SCAN_BLOCKS, 256, 0, stream>>>(deg, locx, bsum);
    scan_s2<<<1, 256, 0, stream>>>(bsum, bpre);
    scan_s3<<<SCAN_BLOCKS, 256, 0, stream>>>(deg, locx, bpre, offsets, cursor);
    fill_csr<<<(N_EDGES + 255) / 256, 256, 0, stream>>>(ei, cursor, csr_src, flags);
    graph_bounds<<<(N_GRAPHS + 1 + 255) / 256, 256, 0, stream>>>(batch, gstart, flags);

    embed_kernel<<<N_NODES / 4, 256, 0, stream>>>(x, x_emb1, x_emb2, h, flags);

    for (int l = 0; l < NLAYER; l++) {
        aggregate_kernel<<<N_NODES / 4, 256, 0, stream>>>(
            h, aggr, offsets, csr_src, Ccnt,
            edge_e1 + (size_t)l * 5 * EMB, edge_e2 + (size_t)l * 3 * EMB);
        int mtilesS = stripRows / 128;
        for (int s = 0; s < nstrip; s++) {
            size_t r0 = (size_t)s * stripRows;
            gemm_layer<<<mtilesS * (HID_P / 128), 256, 0, stream>>>(
                aggr + r0 * EMB_P, W1t + (size_t)l * HID_P * EMB_P,
                b1p + (size_t)l * HID_P, hdn,
                EMB_P, EMB_P, EMB_P, HID_P, mtilesS, HID_P / 128, HID_P, 1);
            gemm_layer<<<mtilesS * (NP2 / 128), 256, 0, stream>>>(
                hdn, W2t + (size_t)l * NP2 * HID_P,
                b2p + (size_t)l * NP2, h + r0 * EMB_P,
                HID_P, HID_P, HID_P, EMB_P, mtilesS, NP2 / 128, EMB_P, (l < NLAYER - 1) ? 1 : 0);
        }
    }

    pool_kernel<<<N_GRAPHS / 4, 256, 0, stream>>>(h, gstart, hg_pre);

    gemm_bf16<<<dim3(FEAT / 128, G_P / 128), 256, 0, stream>>>(
        hg_pre, featWt, fb, hgbuf, out,
        EMB_P, EMB_P, EMB_P, FEAT, N_GRAPHS, FEAT, 0);
    gemm_bf16<<<dim3(OUTD / 128, G_P / 128), 256, 0, stream>>>(
        hgbuf, p0Wt, p0b, pbuf0, nullptr,
        FEAT, FEAT, FEAT, OUTD, N_GRAPHS, OUTD, 1);
    gemm_bf16<<<dim3(OUTD / 128, G_P / 128), 256, 0, stream>>>(
        pbuf0, p1Wt, p1b, pbuf1, nullptr,
        OUTD, OUTD, OUTD, OUTD, N_GRAPHS, OUTD, 1);
    gemm_bf16<<<dim3(OUTD / 128, G_P / 128), 256, 0, stream>>>(
        pbuf1, p2Wt, p2b, nullptr, out + (size_t)N_GRAPHS * FEAT,
        OUTD, OUTD, OUTD, OUTD, N_GRAPHS, OUTD, 0);
}